// Round 1
// baseline (119.291 us; speedup 1.0000x reference)
//
#include <hip/hip_runtime.h>

// SparseLinear: out[4096,256] = COO(row_idx,col_idx,vals) @ weight[32000,256] + bias
// row_idx is SORTED -> each output row is a contiguous nnz segment.
// Strategy: one wave (64 lanes) per output row. Lane l accumulates outputs
// [4l, 4l+4) as a float4 (16 B/lane coalesced gather of each weight row).
// Segment bounds found by per-wave binary search (avg 64 nnz/row, ~18 steps).
// No atomics, no workspace.

constexpr int BATCH = 4096;
constexpr int ROWS_PER_BLOCK = 4;   // 4 waves/block, 256 threads

__global__ __launch_bounds__(256, 4) void sparse_linear_kernel(
    const int*   __restrict__ row_idx,
    const int*   __restrict__ col_idx,
    const float* __restrict__ vals,
    const float* __restrict__ weight,   // [32000, 256]
    const float* __restrict__ bias,     // [256]
    float*       __restrict__ out,      // [4096, 256]
    int nnz)
{
    const int wave = threadIdx.x >> 6;
    const int lane = threadIdx.x & 63;
    const int r    = blockIdx.x * ROWS_PER_BLOCK + wave;

    // lower_bound(r): first index with row_idx[i] >= r
    int lo = 0, hi = nnz;
    while (lo < hi) {
        int mid = (lo + hi) >> 1;
        if (row_idx[mid] < r) lo = mid + 1; else hi = mid;
    }
    const int start = lo;
    // lower_bound(r+1), restarting from `start`
    hi = nnz;
    while (lo < hi) {
        int mid = (lo + hi) >> 1;
        if (row_idx[mid] < r + 1) lo = mid + 1; else hi = mid;
    }
    const int end = lo;

    const float4* __restrict__ W = reinterpret_cast<const float4*>(weight); // row stride 64

    float4 a0 = make_float4(0.f, 0.f, 0.f, 0.f);
    float4 a1 = a0, a2 = a0, a3 = a0;

    int k = start;
    // Unroll x4: four independent gather chains in flight per wave.
    for (; k + 4 <= end; k += 4) {
        const int   c0 = col_idx[k + 0], c1 = col_idx[k + 1];
        const int   c2 = col_idx[k + 2], c3 = col_idx[k + 3];
        const float v0 = vals[k + 0], v1 = vals[k + 1];
        const float v2 = vals[k + 2], v3 = vals[k + 3];
        const float4 w0 = W[(size_t)c0 * 64 + lane];
        const float4 w1 = W[(size_t)c1 * 64 + lane];
        const float4 w2 = W[(size_t)c2 * 64 + lane];
        const float4 w3 = W[(size_t)c3 * 64 + lane];
        a0.x = fmaf(v0, w0.x, a0.x); a0.y = fmaf(v0, w0.y, a0.y);
        a0.z = fmaf(v0, w0.z, a0.z); a0.w = fmaf(v0, w0.w, a0.w);
        a1.x = fmaf(v1, w1.x, a1.x); a1.y = fmaf(v1, w1.y, a1.y);
        a1.z = fmaf(v1, w1.z, a1.z); a1.w = fmaf(v1, w1.w, a1.w);
        a2.x = fmaf(v2, w2.x, a2.x); a2.y = fmaf(v2, w2.y, a2.y);
        a2.z = fmaf(v2, w2.z, a2.z); a2.w = fmaf(v2, w2.w, a2.w);
        a3.x = fmaf(v3, w3.x, a3.x); a3.y = fmaf(v3, w3.y, a3.y);
        a3.z = fmaf(v3, w3.z, a3.z); a3.w = fmaf(v3, w3.w, a3.w);
    }
    for (; k < end; ++k) {
        const int   c = col_idx[k];
        const float v = vals[k];
        const float4 w = W[(size_t)c * 64 + lane];
        a0.x = fmaf(v, w.x, a0.x); a0.y = fmaf(v, w.y, a0.y);
        a0.z = fmaf(v, w.z, a0.z); a0.w = fmaf(v, w.w, a0.w);
    }

    float4 acc;
    acc.x = (a0.x + a1.x) + (a2.x + a3.x);
    acc.y = (a0.y + a1.y) + (a2.y + a3.y);
    acc.z = (a0.z + a1.z) + (a2.z + a3.z);
    acc.w = (a0.w + a1.w) + (a2.w + a3.w);

    const float4 b = reinterpret_cast<const float4*>(bias)[lane];
    float4 o;
    o.x = acc.x + b.x; o.y = acc.y + b.y;
    o.z = acc.z + b.z; o.w = acc.w + b.w;

    reinterpret_cast<float4*>(out)[(size_t)r * 64 + lane] = o;
}

extern "C" void kernel_launch(void* const* d_in, const int* in_sizes, int n_in,
                              void* d_out, int out_size, void* d_ws, size_t ws_size,
                              hipStream_t stream)
{
    const int*   row_idx = (const int*)  d_in[0];
    const int*   col_idx = (const int*)  d_in[1];
    const float* vals    = (const float*)d_in[2];
    const float* weight  = (const float*)d_in[3];
    const float* bias    = (const float*)d_in[4];
    float*       out     = (float*)      d_out;
    const int    nnz     = in_sizes[0];

    dim3 grid(BATCH / ROWS_PER_BLOCK);
    dim3 block(256);
    hipLaunchKernelGGL(sparse_linear_kernel, grid, block, 0, stream,
                       row_idx, col_idx, vals, weight, bias, out, nnz);
}

// Round 2
// 114.588 us; speedup vs baseline: 1.0410x; 1.0410x over previous
//
#include <hip/hip_runtime.h>

// SparseLinear: out[4096,256] = COO(row_idx,col_idx,vals) @ weight[32000,256] + bias
// row_idx SORTED. Two kernels:
//   1. build_row_ptr: scan nnz once, emit CSR-style row_ptr[4097] into d_ws
//      (removes the per-wave dual binary search: 36 dependent loads -> 2).
//   2. main: ONE ROW PER BLOCK, 4 waves/block each taking a contiguous 1/4
//      chunk of the row's nnz segment; float4-per-lane gather of weight rows
//      (64 lanes x 16 B = 1 KB coalesced per load); LDS reduce of 4 partials.
//      4096 blocks x 4 waves = 16384 waves -> 32 waves/CU resident (vs 16
//      before; round-1 was grid-occupancy-limited at 35%).

constexpr int BATCH = 4096;

__global__ void build_row_ptr(const int* __restrict__ row_idx, int nnz,
                              int* __restrict__ ptr)
{
    const int i = blockIdx.x * blockDim.x + threadIdx.x;
    if (i >= nnz) return;
    const int r  = row_idx[i];
    const int rn = (i + 1 < nnz) ? row_idx[i + 1] : BATCH;
    // only boundary threads loop (sorted input -> gaps are tiny)
    for (int rr = r + 1; rr <= rn; ++rr) ptr[rr] = i + 1;
    if (i == 0)
        for (int rr = 0; rr <= r; ++rr) ptr[rr] = 0;
}

__global__ __launch_bounds__(256, 8) void sparse_linear_kernel(
    const int*   __restrict__ col_idx,
    const float* __restrict__ vals,
    const float* __restrict__ weight,   // [32000, 256]
    const float* __restrict__ bias,     // [256]
    const int*   __restrict__ ptr,      // [4097]
    float*       __restrict__ out)      // [4096, 256]
{
    __shared__ float4 part[4][64];

    const int wave = threadIdx.x >> 6;
    const int lane = threadIdx.x & 63;
    const int r    = blockIdx.x;

    const int start = ptr[r];
    const int end   = ptr[r + 1];
    const int len   = end - start;
    const int chunk = (len + 3) >> 2;

    int k  = start + wave * chunk;
    int ke = min(k + chunk, end);

    const float4* __restrict__ W = reinterpret_cast<const float4*>(weight); // row stride 64

    float4 a0 = make_float4(0.f, 0.f, 0.f, 0.f);
    float4 a1 = a0, a2 = a0, a3 = a0;

    // Unroll x4: four independent gather chains in flight per wave.
    for (; k + 4 <= ke; k += 4) {
        const int   c0 = col_idx[k + 0], c1 = col_idx[k + 1];
        const int   c2 = col_idx[k + 2], c3 = col_idx[k + 3];
        const float v0 = vals[k + 0], v1 = vals[k + 1];
        const float v2 = vals[k + 2], v3 = vals[k + 3];
        const float4 w0 = W[(size_t)c0 * 64 + lane];
        const float4 w1 = W[(size_t)c1 * 64 + lane];
        const float4 w2 = W[(size_t)c2 * 64 + lane];
        const float4 w3 = W[(size_t)c3 * 64 + lane];
        a0.x = fmaf(v0, w0.x, a0.x); a0.y = fmaf(v0, w0.y, a0.y);
        a0.z = fmaf(v0, w0.z, a0.z); a0.w = fmaf(v0, w0.w, a0.w);
        a1.x = fmaf(v1, w1.x, a1.x); a1.y = fmaf(v1, w1.y, a1.y);
        a1.z = fmaf(v1, w1.z, a1.z); a1.w = fmaf(v1, w1.w, a1.w);
        a2.x = fmaf(v2, w2.x, a2.x); a2.y = fmaf(v2, w2.y, a2.y);
        a2.z = fmaf(v2, w2.z, a2.z); a2.w = fmaf(v2, w2.w, a2.w);
        a3.x = fmaf(v3, w3.x, a3.x); a3.y = fmaf(v3, w3.y, a3.y);
        a3.z = fmaf(v3, w3.z, a3.z); a3.w = fmaf(v3, w3.w, a3.w);
    }
    for (; k < ke; ++k) {
        const int   c = col_idx[k];
        const float v = vals[k];
        const float4 w = W[(size_t)c * 64 + lane];
        a0.x = fmaf(v, w.x, a0.x); a0.y = fmaf(v, w.y, a0.y);
        a0.z = fmaf(v, w.z, a0.z); a0.w = fmaf(v, w.w, a0.w);
    }

    float4 acc;
    acc.x = (a0.x + a1.x) + (a2.x + a3.x);
    acc.y = (a0.y + a1.y) + (a2.y + a3.y);
    acc.z = (a0.z + a1.z) + (a2.z + a3.z);
    acc.w = (a0.w + a1.w) + (a2.w + a3.w);

    part[wave][lane] = acc;
    __syncthreads();

    if (wave == 0) {
        const float4 p0 = part[0][lane], p1 = part[1][lane];
        const float4 p2 = part[2][lane], p3 = part[3][lane];
        const float4 b  = reinterpret_cast<const float4*>(bias)[lane];
        float4 o;
        o.x = ((p0.x + p1.x) + (p2.x + p3.x)) + b.x;
        o.y = ((p0.y + p1.y) + (p2.y + p3.y)) + b.y;
        o.z = ((p0.z + p1.z) + (p2.z + p3.z)) + b.z;
        o.w = ((p0.w + p1.w) + (p2.w + p3.w)) + b.w;
        reinterpret_cast<float4*>(out)[(size_t)r * 64 + lane] = o;
    }
}

extern "C" void kernel_launch(void* const* d_in, const int* in_sizes, int n_in,
                              void* d_out, int out_size, void* d_ws, size_t ws_size,
                              hipStream_t stream)
{
    const int*   row_idx = (const int*)  d_in[0];
    const int*   col_idx = (const int*)  d_in[1];
    const float* vals    = (const float*)d_in[2];
    const float* weight  = (const float*)d_in[3];
    const float* bias    = (const float*)d_in[4];
    float*       out     = (float*)      d_out;
    const int    nnz     = in_sizes[0];

    int* row_ptr = (int*)d_ws;  // 4097 ints = 16.4 KB of scratch

    hipLaunchKernelGGL(build_row_ptr, dim3((nnz + 255) / 256), dim3(256), 0, stream,
                       row_idx, nnz, row_ptr);
    hipLaunchKernelGGL(sparse_linear_kernel, dim3(BATCH), dim3(256), 0, stream,
                       col_idx, vals, weight, bias, row_ptr, out);
}

// Round 3
// 105.136 us; speedup vs baseline: 1.1346x; 1.0899x over previous
//
#include <hip/hip_runtime.h>
#include <hip/hip_bf16.h>

// SparseLinear: out[4096,256] = COO @ weight[32000,256] + bias (fp32).
// Round-3 structure:
//  1. prep_kernel (fused): weight fp32->bf16 into d_ws (halves gather volume
//     268->134 MB; halves L2 line requests per gather) + CSR row_ptr build.
//  2. sparse_linear_bf16: 2 waves per output row (8192 waves = exactly one
//     32-wave/CU residency pass). Per round: 8 wave-uniform scalar idx/val
//     loads (readfirstlane -> s_load), then 8 independent 512B row-gathers
//     (uint2 = 4 bf16/lane) issued back-to-back; fp32 accumulate.
// Error budget: bf16 weight round-off adds ~3-5e-3 absmax vs 3.06e-2 thresh.

constexpr int BATCH = 4096;

__device__ inline unsigned short f2bf(float f) {   // fp32 -> bf16 RNE
    unsigned u = __float_as_uint(f);
    unsigned r = (u + 0x7FFFu + ((u >> 16) & 1u)) >> 16;
    return (unsigned short)r;
}

__global__ __launch_bounds__(256) void prep_kernel(
    const float* __restrict__ weight,          // [32000*256] fp32
    unsigned short* __restrict__ wb,           // [32000*256] bf16 out (ws)
    const int* __restrict__ row_idx, int nnz,
    int* __restrict__ ptr,                     // [4097] out (ws)
    int n_w4, int conv_blocks)
{
    if ((int)blockIdx.x < conv_blocks) {
        const int t = blockIdx.x * 256 + threadIdx.x;   // one float4 per thread
        if (t < n_w4) {
            const float4 f = reinterpret_cast<const float4*>(weight)[t];
            ushort4 o;
            o.x = f2bf(f.x); o.y = f2bf(f.y); o.z = f2bf(f.z); o.w = f2bf(f.w);
            reinterpret_cast<ushort4*>(wb)[t] = o;
        }
    } else {
        const int i = (blockIdx.x - conv_blocks) * 256 + threadIdx.x;
        if (i >= nnz) return;
        const int r  = row_idx[i];
        const int rn = (i + 1 < nnz) ? row_idx[i + 1] : BATCH;
        for (int rr = r + 1; rr <= rn; ++rr) ptr[rr] = i + 1;
        if (i == 0)
            for (int rr = 0; rr <= r; ++rr) ptr[rr] = 0;
    }
}

__device__ inline void fma_bf(float v, uint2 w, float4& acc) {
    acc.x = fmaf(v, __uint_as_float(w.x << 16),          acc.x);
    acc.y = fmaf(v, __uint_as_float(w.x & 0xFFFF0000u), acc.y);
    acc.z = fmaf(v, __uint_as_float(w.y << 16),          acc.z);
    acc.w = fmaf(v, __uint_as_float(w.y & 0xFFFF0000u), acc.w);
}

__global__ __launch_bounds__(256, 8) void sparse_linear_bf16(
    const int*            __restrict__ col_idx,
    const float*          __restrict__ vals,
    const unsigned short* __restrict__ wb,     // [32000,256] bf16
    const float*          __restrict__ bias,   // [256]
    const int*            __restrict__ ptr,    // [4097]
    float*                __restrict__ out,    // [4096,256]
    int nnz)
{
    __shared__ float4 part[4][64];

    const int wave = threadIdx.x >> 6;
    const int lane = threadIdx.x & 63;
    const int rloc = wave >> 1;                 // row within block (0..1)
    const int half = wave & 1;                  // which half-segment
    const int r    = blockIdx.x * 2 + rloc;

    const int start = ptr[r];
    const int end   = ptr[r + 1];
    const int chunk = (end - start + 1) >> 1;

    int k  = start + half * chunk;
    int ke = min(k + chunk, end);

    const uint2* __restrict__ W = reinterpret_cast<const uint2*>(wb); // row stride 64

    float4 acc = make_float4(0.f, 0.f, 0.f, 0.f);

    while (k + 8 <= ke) {
        const int kb = __builtin_amdgcn_readfirstlane(k);
        const int   c0 = col_idx[kb + 0], c1 = col_idx[kb + 1];
        const int   c2 = col_idx[kb + 2], c3 = col_idx[kb + 3];
        const int   c4 = col_idx[kb + 4], c5 = col_idx[kb + 5];
        const int   c6 = col_idx[kb + 6], c7 = col_idx[kb + 7];
        const float v0 = vals[kb + 0], v1 = vals[kb + 1];
        const float v2 = vals[kb + 2], v3 = vals[kb + 3];
        const float v4 = vals[kb + 4], v5 = vals[kb + 5];
        const float v6 = vals[kb + 6], v7 = vals[kb + 7];
        const uint2 w0 = W[(size_t)c0 * 64 + lane];
        const uint2 w1 = W[(size_t)c1 * 64 + lane];
        const uint2 w2 = W[(size_t)c2 * 64 + lane];
        const uint2 w3 = W[(size_t)c3 * 64 + lane];
        const uint2 w4 = W[(size_t)c4 * 64 + lane];
        const uint2 w5 = W[(size_t)c5 * 64 + lane];
        const uint2 w6 = W[(size_t)c6 * 64 + lane];
        const uint2 w7 = W[(size_t)c7 * 64 + lane];
        fma_bf(v0, w0, acc); fma_bf(v1, w1, acc);
        fma_bf(v2, w2, acc); fma_bf(v3, w3, acc);
        fma_bf(v4, w4, acc); fma_bf(v5, w5, acc);
        fma_bf(v6, w6, acc); fma_bf(v7, w7, acc);
        k += 8;
    }

    const int rem = ke - k;                     // 0..7
    if (rem > 0) {
        const int kb = __builtin_amdgcn_readfirstlane(k);
        #pragma unroll
        for (int j = 0; j < 8; ++j) {
            const int   kk = min(kb + j, nnz - 1);   // stay in-bounds when masked
            const int   c  = col_idx[kk];
            const float v  = (j < rem) ? vals[kk] : 0.0f;
            const uint2 w  = W[(size_t)c * 64 + lane];
            fma_bf(v, w, acc);
        }
    }

    part[wave][lane] = acc;
    __syncthreads();

    if (threadIdx.x < 128) {                    // 2 waves finalize 2 rows
        const int rl = threadIdx.x >> 6;
        const int ln = threadIdx.x & 63;
        const float4 p0 = part[2 * rl + 0][ln];
        const float4 p1 = part[2 * rl + 1][ln];
        const float4 b  = reinterpret_cast<const float4*>(bias)[ln];
        float4 o;
        o.x = (p0.x + p1.x) + b.x;
        o.y = (p0.y + p1.y) + b.y;
        o.z = (p0.z + p1.z) + b.z;
        o.w = (p0.w + p1.w) + b.w;
        reinterpret_cast<float4*>(out)[(size_t)(blockIdx.x * 2 + rl) * 64 + ln] = o;
    }
}

extern "C" void kernel_launch(void* const* d_in, const int* in_sizes, int n_in,
                              void* d_out, int out_size, void* d_ws, size_t ws_size,
                              hipStream_t stream)
{
    const int*   row_idx = (const int*)  d_in[0];
    const int*   col_idx = (const int*)  d_in[1];
    const float* vals    = (const float*)d_in[2];
    const float* weight  = (const float*)d_in[3];
    const float* bias    = (const float*)d_in[4];
    float*       out     = (float*)      d_out;
    const int    nnz     = in_sizes[0];
    const int    w_elems = in_sizes[3];          // 32000*256

    unsigned short* wb      = (unsigned short*)d_ws;            // 16.4 MB
    int*            row_ptr = (int*)((char*)d_ws + (32u << 20)); // @32 MiB

    const int n_w4        = w_elems / 4;                 // 2,048,000
    const int conv_blocks = (n_w4 + 255) / 256;          // 8000
    const int rptr_blocks = (nnz + 255) / 256;           // 1024

    hipLaunchKernelGGL(prep_kernel, dim3(conv_blocks + rptr_blocks), dim3(256), 0, stream,
                       weight, wb, row_idx, nnz, row_ptr, n_w4, conv_blocks);
    hipLaunchKernelGGL(sparse_linear_bf16, dim3(BATCH / 2), dim3(256), 0, stream,
                       col_idx, vals, wb, bias, row_ptr, out, nnz);
}